// Round 4
// baseline (151.153 us; speedup 1.0000x reference)
//
#include <hip/hip_runtime.h>
#include <hip/hip_bf16.h>

#define SM_N 4096

typedef __attribute__((ext_vector_type(8))) short bf16x8;  // 8 bf16 = 4 VGPRs
typedef __attribute__((ext_vector_type(4))) short bf16x4;  // 4 bf16 = 2 VGPRs
typedef __attribute__((ext_vector_type(4))) float f32x4;

union Frag8 { bf16x8 v; bf16x4 h[2]; unsigned u[4]; };

// pack 2 floats -> 1 dword of 2 bf16 (RTNE); compiler lowers to v_cvt_pk_bf16_f32
static __device__ __forceinline__ unsigned pk2(float lo, float hi) {
    __hip_bfloat162 t = __float22bfloat162_rn(float2{lo, hi});
    union { __hip_bfloat162 b; unsigned u; } c; c.b = t;
    return c.u;
}

// elu(x) = median(x, exp(x)-1, 0): for x>0 median is x (expm1>x>0); for x<0
// median is expm1 (x < expm1 < 0). Handles exp overflow (inf -> picks x) and
// underflow (expm1->-1 -> picks -1). Branchless: mul+exp+add+med3.
static __device__ __forceinline__ float elu(float x) {
    return __builtin_amdgcn_fmed3f(x, __expf(x) - 1.0f, 0.0f);
}

// prep: transpose + bf16-convert the hypernet weights into workspace.
//   w1t[b][h][k] = bf16(w1[b][k][h])   (96x16 per block)
//   w2t[b][j][h] = bf16(w2[b][h][j])   (16x96 per block)
__global__ __launch_bounds__(256) void prep_weights(
    const float* __restrict__ w1, const float* __restrict__ w2,
    __hip_bfloat16* __restrict__ w1t, __hip_bfloat16* __restrict__ w2t)
{
    const int b = blockIdx.x, t = threadIdx.x;
    const float* __restrict__ w1b = w1 + (size_t)b * 1536;
    const float* __restrict__ w2b = w2 + (size_t)b * 1536;
    __hip_bfloat16* __restrict__ o1 = w1t + (size_t)b * 1536;
    __hip_bfloat16* __restrict__ o2 = w2t + (size_t)b * 1536;
    const int lo = t & 15, hb = (t >> 4) * 6;
#pragma unroll
    for (int i = 0; i < 6; ++i) {
        const int h = hb + i;
        o1[h * 16 + lo] = __float2bfloat16(w1b[lo * 96 + h]);  // k = lo
        o2[lo * 96 + h] = __float2bfloat16(w2b[h * 16 + lo]);  // j = lo
    }
}

// Main: swapped-operand MFMA hypernet (same math/layout as R2, verified):
//   GEMM1: D1[h][t] = W1^T x X^T (K=16 zero-padded to 32)
//   GEMM2: D2[j][t] = W2^T x H^T (K=96 = 3x32)
// Lane l (g=l>>4, ln=l&15) owns tile t=q*16+ln of its wave's tile-row th.
__global__ __launch_bounds__(256) void adapter_mfma(
    const float* __restrict__ sm,
    const float* __restrict__ b1,    // [256][96]
    const float* __restrict__ emb_h, // [256][64][8]
    const float* __restrict__ emb_w, // [256][64][8]
    const float* __restrict__ b2,    // [256][16]
    const float* __restrict__ scales,// [256][16]
    const ushort* __restrict__ w1t,  // [256][96][16] bf16
    const ushort* __restrict__ w2t,  // [256][16][96] bf16
    float* __restrict__ out)
{
    const int wg   = blockIdx.x;          // 0..4095 (16 wg per 256x256 block)
    const int b    = wg >> 4;
    const int obi  = b >> 4, ibi = b & 15;
    const int tid  = threadIdx.x;
    const int wave = tid >> 6;
    const int lane = tid & 63;
    const int g    = lane >> 4;
    const int ln   = lane & 15;
    const int th   = (wg & 15) * 4 + wave;   // tile row 0..63

    const ushort* __restrict__ w1tb = w1t + (size_t)b * 1536;
    const ushort* __restrict__ w2tb = w2t + (size_t)b * 1536;

    // A1[hg]: row h=hg*16+ln, k-slots 4g..4g+3 = 4 consecutive bf16; high half 0
    Frag8 A1[6];
#pragma unroll
    for (int hg = 0; hg < 6; ++hg) {
        A1[hg].h[0] = *reinterpret_cast<const bf16x4*>(w1tb + (hg * 16 + ln) * 16 + 4 * g);
        A1[hg].h[1] = (bf16x4){0, 0, 0, 0};
    }
    // A2[kk]: row j=ln; slots i<4 -> h=32kk+4g+i, i>=4 -> h=32kk+16+4g+(i-4)
    Frag8 A2[3];
#pragma unroll
    for (int kk = 0; kk < 3; ++kk) {
        A2[kk].h[0] = *reinterpret_cast<const bf16x4*>(w2tb + ln * 96 + 32 * kk + 4 * g);
        A2[kk].h[1] = *reinterpret_cast<const bf16x4*>(w2tb + ln * 96 + 32 * kk + 16 + 4 * g);
    }
    const float* __restrict__ b1b = b1 + (size_t)b * 96;
    f32x4 B1C[6];
#pragma unroll
    for (int hg = 0; hg < 6; ++hg)
        B1C[hg] = *reinterpret_cast<const f32x4*>(b1b + hg * 16 + 4 * g);
    const f32x4 b2f = *reinterpret_cast<const f32x4*>(b2 + (size_t)b * 16 + 4 * g);
    const f32x4 scf = *reinterpret_cast<const f32x4*>(scales + (size_t)b * 16 + 4 * g);

    // positional-emb: g<2 lanes read emb_h[b][th] (q-invariant, step 0);
    // g>=2 lanes read emb_w[b][q*16+ln] (step 16 rows * 8 floats = 128)
    const float* __restrict__ ebase = (g < 2)
        ? emb_h + ((size_t)b * 64 + th) * 8 + 4 * g
        : emb_w + ((size_t)b * 64 + ln) * 8 + 4 * (g - 2);
    const int estep = (g < 2) ? 0 : 128;

    const int row0 = obi * 256 + th * 4;
    const float* __restrict__ srow = sm  + (size_t)(row0 + g) * SM_N + ibi * 256 + ln * 4;
    float*       __restrict__ drow = out + (size_t)(row0 + g) * SM_N + ibi * 256 + ln * 4;

#pragma unroll 2
    for (int q = 0; q < 4; ++q) {
        const f32x4 x4 = *reinterpret_cast<const f32x4*>(srow + q * 64);
        const f32x4 ef = *reinterpret_cast<const f32x4*>(ebase + q * estep);

        Frag8 xb;
        xb.u[0] = pk2(x4[0], x4[1]);
        xb.u[1] = pk2(x4[2], x4[3]);
        xb.u[2] = 0; xb.u[3] = 0;

        f32x4 D1[6];
        D1[0] = __builtin_amdgcn_mfma_f32_16x16x32_bf16(A1[0].v, xb.v, B1C[0] + ef, 0, 0, 0);
#pragma unroll
        for (int hg = 1; hg < 6; ++hg)
            D1[hg] = __builtin_amdgcn_mfma_f32_16x16x32_bf16(A1[hg].v, xb.v, B1C[hg], 0, 0, 0);

        // residual + bias2 (fp32, dominant term stays exact)
        f32x4 acc;
#pragma unroll
        for (int i = 0; i < 4; ++i) acc[i] = fmaf(x4[i], scf[i], b2f[i]);

#pragma unroll
        for (int kk = 0; kk < 3; ++kk) {
            const f32x4 dA = D1[2 * kk], dB = D1[2 * kk + 1];
            Frag8 p;
            p.u[0] = pk2(elu(dA[0]), elu(dA[1]));
            p.u[1] = pk2(elu(dA[2]), elu(dA[3]));
            p.u[2] = pk2(elu(dB[0]), elu(dB[1]));
            p.u[3] = pk2(elu(dB[2]), elu(dB[3]));
            acc = __builtin_amdgcn_mfma_f32_16x16x32_bf16(A2[kk].v, p.v, acc, 0, 0, 0);
        }

        *reinterpret_cast<f32x4*>(drow + q * 64) = acc;
    }
}

extern "C" void kernel_launch(void* const* d_in, const int* in_sizes, int n_in,
                              void* d_out, int out_size, void* d_ws, size_t ws_size,
                              hipStream_t stream) {
    const float* sm     = (const float*)d_in[0];
    const float* w1     = (const float*)d_in[1];
    const float* b1     = (const float*)d_in[2];
    const float* emb_h  = (const float*)d_in[3];
    const float* emb_w  = (const float*)d_in[4];
    const float* w2     = (const float*)d_in[5];
    const float* b2     = (const float*)d_in[6];
    const float* scales = (const float*)d_in[7];
    float* out = (float*)d_out;

    __hip_bfloat16* w1t = (__hip_bfloat16*)d_ws;                    // 768 KB
    __hip_bfloat16* w2t = (__hip_bfloat16*)((char*)d_ws + 786432);  // 768 KB

    prep_weights<<<dim3(256), dim3(256), 0, stream>>>(w1, w2, w1t, w2t);
    adapter_mfma<<<dim3(4096), dim3(256), 0, stream>>>(
        sm, b1, emb_h, emb_w, b2, scales, (const ushort*)w1t, (const ushort*)w2t, out);
}

// Round 6
// 142.236 us; speedup vs baseline: 1.0627x; 1.0627x over previous
//
#include <hip/hip_runtime.h>
#include <hip/hip_bf16.h>

#define SM_N 4096

typedef __attribute__((ext_vector_type(8))) short bf16x8;  // 8 bf16 = 4 VGPRs
typedef __attribute__((ext_vector_type(4))) short bf16x4;  // 4 bf16 = 2 VGPRs
typedef __attribute__((ext_vector_type(4))) float f32x4;

union Frag8 { bf16x8 v; bf16x4 h[2]; unsigned u[4]; };

// pack 2 floats -> 1 dword of 2 bf16 (RTNE); compiler lowers to v_cvt_pk_bf16_f32
static __device__ __forceinline__ unsigned pk2(float lo, float hi) {
    __hip_bfloat162 t = __float22bfloat162_rn(float2{lo, hi});
    union { __hip_bfloat162 b; unsigned u; } c; c.b = t;
    return c.u;
}

// elu(x) = median(x, exp(x)-1, 0) — exact branchless ELU
static __device__ __forceinline__ float elu(float x) {
    return __builtin_amdgcn_fmed3f(x, __expf(x) - 1.0f, 0.0f);
}

// prep: transpose + bf16-convert the hypernet weights into workspace.
//   w1t[b][h][k] = bf16(w1[b][k][h])   (96x16 per block)
//   w2t[b][j][h] = bf16(w2[b][h][j])   (16x96 per block)
__global__ __launch_bounds__(256) void prep_weights(
    const float* __restrict__ w1, const float* __restrict__ w2,
    __hip_bfloat16* __restrict__ w1t, __hip_bfloat16* __restrict__ w2t)
{
    const int b = blockIdx.x, t = threadIdx.x;
    const float* __restrict__ w1b = w1 + (size_t)b * 1536;
    const float* __restrict__ w2b = w2 + (size_t)b * 1536;
    __hip_bfloat16* __restrict__ o1 = w1t + (size_t)b * 1536;
    __hip_bfloat16* __restrict__ o2 = w2t + (size_t)b * 1536;
    const int lo = t & 15, hb = (t >> 4) * 6;
#pragma unroll
    for (int i = 0; i < 6; ++i) {
        const int h = hb + i;
        o1[h * 16 + lo] = __float2bfloat16(w1b[lo * 96 + h]);  // k = lo
        o2[lo * 96 + h] = __float2bfloat16(w2b[h * 16 + lo]);  // j = lo
    }
}

// Main: swapped-operand MFMA hypernet (verified layout, R2-R4):
//   GEMM1: D1[h][t] = W1^T x X^T (K=16 zero-padded to 32)
//   GEMM2: D2[j][t] = W2^T x H^T (K=96 = 3x32)
// R5 change: all 4 HBM x-loads hoisted to the top (4x memory parallelism,
// load phase decoupled from the exp/pack/MFMA compute phase).
__global__ __launch_bounds__(256) void adapter_mfma(
    const float* __restrict__ sm,
    const float* __restrict__ b1,    // [256][96]
    const float* __restrict__ emb_h, // [256][64][8]
    const float* __restrict__ emb_w, // [256][64][8]
    const float* __restrict__ b2,    // [256][16]
    const float* __restrict__ scales,// [256][16]
    const ushort* __restrict__ w1t,  // [256][96][16] bf16
    const ushort* __restrict__ w2t,  // [256][16][96] bf16
    float* __restrict__ out)
{
    const int wg   = blockIdx.x;          // 0..4095 (16 wg per 256x256 block)
    const int b    = wg >> 4;
    const int obi  = b >> 4, ibi = b & 15;
    const int tid  = threadIdx.x;
    const int wave = tid >> 6;
    const int lane = tid & 63;
    const int g    = lane >> 4;
    const int ln   = lane & 15;
    const int th   = (wg & 15) * 4 + wave;   // tile row 0..63

    const int row0 = obi * 256 + th * 4;
    const float* __restrict__ srow = sm  + (size_t)(row0 + g) * SM_N + ibi * 256 + ln * 4;
    float*       __restrict__ drow = out + (size_t)(row0 + g) * SM_N + ibi * 256 + ln * 4;

    // ---- hoisted HBM loads: all 4 tiles' x in flight at once ----
    f32x4 xs[4];
#pragma unroll
    for (int q = 0; q < 4; ++q)
        xs[q] = *reinterpret_cast<const f32x4*>(srow + q * 64);

    const ushort* __restrict__ w1tb = w1t + (size_t)b * 1536;
    const ushort* __restrict__ w2tb = w2t + (size_t)b * 1536;

    // A1[hg]: row h=hg*16+ln, k-slots 4g..4g+3 = 4 consecutive bf16; high half 0
    Frag8 A1[6];
#pragma unroll
    for (int hg = 0; hg < 6; ++hg) {
        A1[hg].h[0] = *reinterpret_cast<const bf16x4*>(w1tb + (hg * 16 + ln) * 16 + 4 * g);
        A1[hg].h[1] = (bf16x4){0, 0, 0, 0};
    }
    // A2[kk]: row j=ln; slots i<4 -> h=32kk+4g+i, i>=4 -> h=32kk+16+4g+(i-4)
    Frag8 A2[3];
#pragma unroll
    for (int kk = 0; kk < 3; ++kk) {
        A2[kk].h[0] = *reinterpret_cast<const bf16x4*>(w2tb + ln * 96 + 32 * kk + 4 * g);
        A2[kk].h[1] = *reinterpret_cast<const bf16x4*>(w2tb + ln * 96 + 32 * kk + 16 + 4 * g);
    }
    const float* __restrict__ b1b = b1 + (size_t)b * 96;
    f32x4 B1C[6];
#pragma unroll
    for (int hg = 0; hg < 6; ++hg)
        B1C[hg] = *reinterpret_cast<const f32x4*>(b1b + hg * 16 + 4 * g);
    const f32x4 b2f = *reinterpret_cast<const f32x4*>(b2 + (size_t)b * 16 + 4 * g);
    const f32x4 scf = *reinterpret_cast<const f32x4*>(scales + (size_t)b * 16 + 4 * g);

    // positional-emb: g<2 lanes read emb_h[b][th] (q-invariant, step 0);
    // g>=2 lanes read emb_w[b][q*16+ln] (step 16 rows * 8 floats = 128)
    const float* __restrict__ ebase = (g < 2)
        ? emb_h + ((size_t)b * 64 + th) * 8 + 4 * g
        : emb_w + ((size_t)b * 64 + ln) * 8 + 4 * (g - 2);
    const int estep = (g < 2) ? 0 : 128;

#pragma unroll
    for (int q = 0; q < 4; ++q) {
        const f32x4 x4 = xs[q];
        const f32x4 ef = *reinterpret_cast<const f32x4*>(ebase + q * estep);

        Frag8 xb;
        xb.u[0] = pk2(x4[0], x4[1]);
        xb.u[1] = pk2(x4[2], x4[3]);
        xb.u[2] = 0; xb.u[3] = 0;

        f32x4 D1[6];
        D1[0] = __builtin_amdgcn_mfma_f32_16x16x32_bf16(A1[0].v, xb.v, B1C[0] + ef, 0, 0, 0);
#pragma unroll
        for (int hg = 1; hg < 6; ++hg)
            D1[hg] = __builtin_amdgcn_mfma_f32_16x16x32_bf16(A1[hg].v, xb.v, B1C[hg], 0, 0, 0);

        // residual + bias2 (fp32, dominant term stays exact)
        f32x4 acc;
#pragma unroll
        for (int i = 0; i < 4; ++i) acc[i] = fmaf(x4[i], scf[i], b2f[i]);

#pragma unroll
        for (int kk = 0; kk < 3; ++kk) {
            const f32x4 dA = D1[2 * kk], dB = D1[2 * kk + 1];
            Frag8 p;
            p.u[0] = pk2(elu(dA[0]), elu(dA[1]));
            p.u[1] = pk2(elu(dA[2]), elu(dA[3]));
            p.u[2] = pk2(elu(dB[0]), elu(dB[1]));
            p.u[3] = pk2(elu(dB[2]), elu(dB[3]));
            acc = __builtin_amdgcn_mfma_f32_16x16x32_bf16(A2[kk].v, p.v, acc, 0, 0, 0);
        }

        *reinterpret_cast<f32x4*>(drow + q * 64) = acc;
    }
}

extern "C" void kernel_launch(void* const* d_in, const int* in_sizes, int n_in,
                              void* d_out, int out_size, void* d_ws, size_t ws_size,
                              hipStream_t stream) {
    const float* sm     = (const float*)d_in[0];
    const float* w1     = (const float*)d_in[1];
    const float* b1     = (const float*)d_in[2];
    const float* emb_h  = (const float*)d_in[3];
    const float* emb_w  = (const float*)d_in[4];
    const float* w2     = (const float*)d_in[5];
    const float* b2     = (const float*)d_in[6];
    const float* scales = (const float*)d_in[7];
    float* out = (float*)d_out;

    __hip_bfloat16* w1t = (__hip_bfloat16*)d_ws;                    // 768 KB
    __hip_bfloat16* w2t = (__hip_bfloat16*)((char*)d_ws + 786432);  // 768 KB

    prep_weights<<<dim3(256), dim3(256), 0, stream>>>(w1, w2, w1t, w2t);
    adapter_mfma<<<dim3(4096), dim3(256), 0, stream>>>(
        sm, b1, emb_h, emb_w, b2, scales, (const ushort*)w1t, (const ushort*)w2t, out);
}